// Round 3
// baseline (139.542 us; speedup 1.0000x reference)
//
#include <hip/hip_runtime.h>
#include <math.h>

#define HW_PIX 65536   // 256*256
#define TDIM 512
#define MAGIC 0x5A17C0DEu

typedef float f4 __attribute__((ext_vector_type(4)));

__device__ __forceinline__ float wred64(float v) {
#pragma unroll
    for (int off = 32; off > 0; off >>= 1) v += __shfl_xor(v, off, 64);
    return v;
}

__device__ __forceinline__ f4 ld4(const float* p) { return *(const f4*)p; }
__device__ __forceinline__ void st4nt(float* p, f4 v) {
    __builtin_nontemporal_store(v, (f4*)p);
}

// ws layout (floats):
//  [b*8 + 0..4]  : u0,u1,u2,s, d0p(=tn-2s)   per batch b = 0..15
//  [128 + 0..31] : fully-baked constants (see prep path, blk 16)
//  [160 + 0..16] : uint flags (magic-compare; poison-proof)
__global__ __launch_bounds__(256) void mega_kernel(
    const float* __restrict__ z,           // (16,3,256,256)
    const float* __restrict__ text_vec,    // (16,512)
    const float* __restrict__ text_proj_w, // (64,512)
    const float* __restrict__ text_proj_b, // (64)
    const float* __restrict__ z_proj_w,    // (64,3)
    const float* __restrict__ z_proj_b,    // (64)
    const float* __restrict__ out_w,       // (3,64)
    const float* __restrict__ out_bias,    // (3)
    const float* __restrict__ log_gamma,
    const float* __restrict__ alpha_p,
    const float* __restrict__ c_p,
    const float* __restrict__ wv,          // (3)
    float* __restrict__ ws,
    float* __restrict__ out)               // (16,3,256,256)
{
    const int blk = blockIdx.x;
    const int tid = threadIdx.x;
    unsigned int* flags = (unsigned int*)(ws + 160);

    if (blk < 16) {
        // ---- producer: per-batch t = text_vec[b] @ W^T + b, then 5 dots ----
        const int b = blk;
        const int o = tid >> 2;   // output channel 0..63
        const int q = tid & 3;    // quarter of the 512-dot
        const float4* tv = (const float4*)(text_vec + (size_t)b * TDIM);
        const float4* wr = (const float4*)(text_proj_w + (size_t)o * TDIM);
        float acc = 0.f;
#pragma unroll 8
        for (int i = q * 32; i < q * 32 + 32; ++i) {
            float4 a = tv[i], w4 = wr[i];
            acc = fmaf(a.x, w4.x, fmaf(a.y, w4.y, fmaf(a.z, w4.z, fmaf(a.w, w4.w, acc))));
        }
        acc += __shfl_xor(acc, 1, 64);
        acc += __shfl_xor(acc, 2, 64);

        __shared__ float t_sh[64];
        if (q == 0) t_sh[o] = acc + text_proj_b[o];
        __syncthreads();

        if (tid < 64) {
            const float t  = t_sh[tid];
            const float w0 = z_proj_w[tid * 3 + 0];
            const float w1 = z_proj_w[tid * 3 + 1];
            const float w2 = z_proj_w[tid * 3 + 2];
            const float zb = z_proj_b[tid];
            float u0 = wred64(w0 * t);
            float u1 = wred64(w1 * t);
            float u2 = wred64(w2 * t);
            float s  = wred64(zb * t);
            float tn = wred64(t * t);
            if (tid == 0) {
                float* pb = ws + b * 8;
                pb[0] = u0; pb[1] = u1; pb[2] = u2; pb[3] = s;
                pb[4] = fmaf(-2.f, s, tn);   // d0 partial (bn added by consumer)
                __threadfence();             // device-scope: flush before publish
                __hip_atomic_store(&flags[b], MAGIC, __ATOMIC_RELEASE,
                                   __HIP_MEMORY_SCOPE_AGENT);
            }
        }
    } else if (blk == 16) {
        // ---- producer: weight-only constants, 22 reductions over 4 waves ----
        const int wave = tid >> 6, lane = tid & 63;
        const float w0 = z_proj_w[lane * 3 + 0];
        const float w1 = z_proj_w[lane * 3 + 1];
        const float w2 = z_proj_w[lane * 3 + 2];
        const float zb = z_proj_b[lane];
        const float o0 = out_w[0 * 64 + lane];
        const float o1 = out_w[1 * 64 + lane];
        const float o2 = out_w[2 * 64 + lane];
        float* c = ws + 128;
        // c: [0..3]=G00,G01,G02,G11 [4..7]=G12,G22,M00,M01
        //    [8..11]=M02,M10,M11,M12 [12..15]=M20,M21,M22,bn
        //    [16..19]=v0,v1,v2,ngamma [20..23]=g0,g1,g2,alpha
        //    [24..27]=cc,W0,W1,W2     [28..31]=ob0,ob1,ob2,pad
        if (wave == 0) {
            float r0 = wred64(w0 * w0), r1 = wred64(w0 * w1), r2 = wred64(w0 * w2);
            float r3 = wred64(w1 * w1), r4 = wred64(w1 * w2), r5 = wred64(w2 * w2);
            if (lane == 0) { c[0]=r0; c[1]=r1; c[2]=r2; c[3]=r3; c[4]=r4; c[5]=r5; }
        } else if (wave == 1) {
            float r0 = wred64(o0 * w0), r1 = wred64(o0 * w1), r2 = wred64(o0 * w2);
            float r3 = wred64(o1 * w0), r4 = wred64(o1 * w1), r5 = wred64(o1 * w2);
            if (lane == 0) { c[6]=r0; c[7]=r1; c[8]=r2; c[9]=r3; c[10]=r4; c[11]=r5; }
        } else if (wave == 2) {
            float r0 = wred64(o2 * w0), r1 = wred64(o2 * w1), r2 = wred64(o2 * w2);
            float r3 = wred64(zb * zb), r4 = wred64(o0 * zb), r5 = wred64(o1 * zb);
            if (lane == 0) { c[12]=r0; c[13]=r1; c[14]=r2; c[15]=r3; c[16]=r4; c[17]=r5; }
        } else {
            float r0 = wred64(o2 * zb), r1 = wred64(w0 * zb);
            float r2 = wred64(w1 * zb), r3 = wred64(w2 * zb);
            if (lane == 0) {
                c[18] = r0;                           // v2
                c[20] = r1; c[21] = r2; c[22] = r3;   // g
                c[19] = -__expf(log_gamma[0]);        // ngamma
                c[23] = alpha_p[0];
                c[24] = c_p[0];
                float a = wv[0], bb = wv[1], d = wv[2];
                float inv = 1.f / (a + bb + d + 1e-8f);
                c[25] = a * inv; c[26] = bb * inv; c[27] = d * inv;  // W0,W1,W2
                c[28] = out_bias[0]; c[29] = out_bias[1]; c[30] = out_bias[2];
                c[31] = 0.f;
            }
        }
        __syncthreads();   // all 4 waves' c[] writes done (vmcnt drained)
        if (tid == 0) {
            __threadfence();
            __hip_atomic_store(&flags[16], MAGIC, __ATOMIC_RELEASE,
                               __HIP_MEMORY_SCOPE_AGENT);
        }
    } else {
        // ---- consumer: one 2048-pixel slice, 8 px/thread ----
        const int pix = blk - 17;
        const int b   = pix >> 5;                          // 32 blocks per batch
        const int p   = ((pix & 31) << 11) + (tid << 3);   // 8 px/thread

        // Issue z loads FIRST: HBM latency hides under the producer's work.
        const float* zp = z + (size_t)b * 3 * HW_PIX + p;
        f4 a0 = ld4(zp),            a1 = ld4(zp + 4);
        f4 b0 = ld4(zp + HW_PIX),   b1 = ld4(zp + HW_PIX + 4);
        f4 c0 = ld4(zp + 2*HW_PIX), c1 = ld4(zp + 2*HW_PIX + 4);
        // anchor: force the loads issued (and completed) before the spin
        asm volatile("" :: "v"(a0[0]), "v"(a1[0]), "v"(b0[0]),
                           "v"(b1[0]), "v"(c0[0]), "v"(c1[0]));

        // Spin (thread 0 only) until this batch's scalars + consts published.
        // Acquire/AGENT invalidates this CU's L1 + XCD L2 -> fresh ws reads.
        if (tid == 0) {
            while (__hip_atomic_load(&flags[b], __ATOMIC_ACQUIRE,
                                     __HIP_MEMORY_SCOPE_AGENT) != MAGIC ||
                   __hip_atomic_load(&flags[16], __ATOMIC_ACQUIRE,
                                     __HIP_MEMORY_SCOPE_AGENT) != MAGIC) {
                __builtin_amdgcn_s_sleep(2);
            }
        }
        __syncthreads();

        const f4* C4 = (const f4*)(ws + 128);
        const f4 f0 = C4[0], f1 = C4[1], f2 = C4[2], f3 = C4[3];
        const f4 f4v = C4[4], f5 = C4[5], f6 = C4[6], f7 = C4[7];
        const float G00=f0[0], G01=f0[1], G02=f0[2], G11=f0[3];
        const float G12=f1[0], G22=f1[1], M00=f1[2], M01=f1[3];
        const float M02=f2[0], M10=f2[1], M11=f2[2], M12=f2[3];
        const float M20=f3[0], M21=f3[1], M22=f3[2], bn =f3[3];
        const float v0=f4v[0], v1=f4v[1], v2=f4v[2], ngamma=f4v[3];
        const float g0=f5[0], g1=f5[1], g2=f5[2], alpha=f5[3];
        const float cc=f6[0], W0=f6[1], W1=f6[2], W2=f6[3];
        const float ob0=f7[0], ob1=f7[1], ob2=f7[2];

        const f4* pb4 = (const f4*)(ws + b * 8);
        const f4 pbA = pb4[0], pbB = pb4[1];
        const float u0=pbA[0], u1=pbA[1], u2=pbA[2], s=pbA[3];
        const float d0 = bn + pbB[0];
        const float e0 = g0 - u0, e1 = g1 - u1, e2 = g2 - u2;

        float X[8], Y[8], Z[8], O0[8], O1[8], O2[8];
#pragma unroll
        for (int j = 0; j < 4; ++j) {
            X[j] = a0[j]; X[j+4] = a1[j];
            Y[j] = b0[j]; Y[j+4] = b1[j];
            Z[j] = c0[j]; Z[j+4] = c1[j];
        }

#pragma unroll
        for (int j = 0; j < 8; ++j) {
            const float x = X[j], y = Y[j], zc = Z[j];
            const float klin = fmaf(x, u0, fmaf(y, u1, fmaf(zc, u2, s)));
            const float quad = x * fmaf(2.f, fmaf(G01, y, G02 * zc), G00 * x)
                             + y * fmaf(2.f, G12 * zc, G11 * y)
                             + G22 * zc * zc;
            const float dist = quad + 2.f * fmaf(e0, x, fmaf(e1, y, e2 * zc)) + d0;
            const float krbf = __expf(ngamma * dist);
            float kp = fmaf(alpha, klin, cc);
            kp = kp * kp;
            const float k = fmaf(W0, krbf, fmaf(W1, klin, W2 * kp));
            const float sig = 1.f / (1.f + __expf(-k));
            const float scale = 1.f + sig;

            const float m0 = fmaf(M00, x, fmaf(M01, y, fmaf(M02, zc, v0)));
            const float m1 = fmaf(M10, x, fmaf(M11, y, fmaf(M12, zc, v1)));
            const float m2 = fmaf(M20, x, fmaf(M21, y, fmaf(M22, zc, v2)));
            O0[j] = fmaf(scale, m0, ob0);
            O1[j] = fmaf(scale, m1, ob1);
            O2[j] = fmaf(scale, m2, ob2);
        }

        float* ob = out + (size_t)b * 3 * HW_PIX + p;
        f4 r;
        r[0]=O0[0]; r[1]=O0[1]; r[2]=O0[2]; r[3]=O0[3]; st4nt(ob, r);
        r[0]=O0[4]; r[1]=O0[5]; r[2]=O0[6]; r[3]=O0[7]; st4nt(ob + 4, r);
        r[0]=O1[0]; r[1]=O1[1]; r[2]=O1[2]; r[3]=O1[3]; st4nt(ob + HW_PIX, r);
        r[0]=O1[4]; r[1]=O1[5]; r[2]=O1[6]; r[3]=O1[7]; st4nt(ob + HW_PIX + 4, r);
        r[0]=O2[0]; r[1]=O2[1]; r[2]=O2[2]; r[3]=O2[3]; st4nt(ob + 2*HW_PIX, r);
        r[0]=O2[4]; r[1]=O2[5]; r[2]=O2[6]; r[3]=O2[7]; st4nt(ob + 2*HW_PIX + 4, r);
    }
}

extern "C" void kernel_launch(void* const* d_in, const int* in_sizes, int n_in,
                              void* d_out, int out_size, void* d_ws, size_t ws_size,
                              hipStream_t stream) {
    const float* z           = (const float*)d_in[0];
    const float* text_vec    = (const float*)d_in[1];
    const float* z_proj_w    = (const float*)d_in[2];
    const float* z_proj_b    = (const float*)d_in[3];
    const float* text_proj_w = (const float*)d_in[4];
    const float* text_proj_b = (const float*)d_in[5];
    const float* out_w       = (const float*)d_in[6];
    const float* out_b       = (const float*)d_in[7];
    const float* log_gamma   = (const float*)d_in[8];
    const float* alpha       = (const float*)d_in[9];
    const float* c           = (const float*)d_in[10];
    const float* w           = (const float*)d_in[11];
    float* out = (float*)d_out;
    float* ws  = (float*)d_ws;
    (void)in_sizes; (void)n_in; (void)out_size; (void)ws_size;

    // 17 producer blocks + 512 consumer blocks; 529 blocks of 4 waves are
    // fully co-resident on 256 CUs (capacity >= 1024), so the spin cannot
    // deadlock regardless of dispatch order.
    mega_kernel<<<529, 256, 0, stream>>>(z, text_vec, text_proj_w, text_proj_b,
                                         z_proj_w, z_proj_b, out_w, out_b,
                                         log_gamma, alpha, c, w, ws, out);
}

// Round 4
// 96.610 us; speedup vs baseline: 1.4444x; 1.4444x over previous
//
#include <hip/hip_runtime.h>
#include <math.h>

#define HW_PIX 65536   // 256*256
#define TDIM 512

typedef float f4 __attribute__((ext_vector_type(4)));

__device__ __forceinline__ float wred64(float v) {
#pragma unroll
    for (int off = 32; off > 0; off >>= 1) v += __shfl_xor(v, off, 64);
    return v;
}

__device__ __forceinline__ f4 ld4(const float* p) { return *(const f4*)p; }
__device__ __forceinline__ void st4(float* p, f4 v) { *(f4*)p = v; }

// ws layout (floats):
//  [b*8 + 0..4]  : u0,u1,u2,s, d0p(=tn-2s)          per batch b = 0..15
//  [128 + 0..31] : fully-baked constants (see prep block 16)
__global__ __launch_bounds__(256) void prep_kernel(
    const float* __restrict__ text_vec,    // (16,512)
    const float* __restrict__ text_proj_w, // (64,512)
    const float* __restrict__ text_proj_b, // (64)
    const float* __restrict__ z_proj_w,    // (64,3)
    const float* __restrict__ z_proj_b,    // (64)
    const float* __restrict__ out_w,       // (3,64)
    const float* __restrict__ out_bias,    // (3)
    const float* __restrict__ log_gamma,
    const float* __restrict__ alpha_p,
    const float* __restrict__ c_p,
    const float* __restrict__ wv,          // (3)
    float* __restrict__ ws)
{
    const int blk = blockIdx.x;
    const int tid = threadIdx.x;

    if (blk < 16) {
        // ---- per-batch: t = text_vec[b] @ text_proj_w^T + b, then 5 dots ----
        const int b = blk;
        const int o = tid >> 2;   // output channel 0..63
        const int q = tid & 3;    // quarter of the 512-dot
        const float4* tv = (const float4*)(text_vec + (size_t)b * TDIM);
        const float4* wr = (const float4*)(text_proj_w + (size_t)o * TDIM);
        float acc = 0.f;
#pragma unroll 8
        for (int i = q * 32; i < q * 32 + 32; ++i) {
            float4 a = tv[i], w4 = wr[i];
            acc = fmaf(a.x, w4.x, fmaf(a.y, w4.y, fmaf(a.z, w4.z, fmaf(a.w, w4.w, acc))));
        }
        acc += __shfl_xor(acc, 1, 64);
        acc += __shfl_xor(acc, 2, 64);

        __shared__ float t_sh[64];
        if (q == 0) t_sh[o] = acc + text_proj_b[o];
        __syncthreads();

        if (tid < 64) {
            const float t  = t_sh[tid];
            const float w0 = z_proj_w[tid * 3 + 0];
            const float w1 = z_proj_w[tid * 3 + 1];
            const float w2 = z_proj_w[tid * 3 + 2];
            const float zb = z_proj_b[tid];
            float u0 = wred64(w0 * t);
            float u1 = wred64(w1 * t);
            float u2 = wred64(w2 * t);
            float s  = wred64(zb * t);
            float tn = wred64(t * t);
            if (tid == 0) {
                float* pb = ws + b * 8;
                pb[0] = u0; pb[1] = u1; pb[2] = u2; pb[3] = s;
                pb[4] = fmaf(-2.f, s, tn);   // d0 partial (bn added in fuse)
            }
        }
    } else {
        // ---- weight-only constants, 22 reductions spread over 4 waves ----
        const int wave = tid >> 6, lane = tid & 63;
        const float w0 = z_proj_w[lane * 3 + 0];
        const float w1 = z_proj_w[lane * 3 + 1];
        const float w2 = z_proj_w[lane * 3 + 2];
        const float zb = z_proj_b[lane];
        const float o0 = out_w[0 * 64 + lane];
        const float o1 = out_w[1 * 64 + lane];
        const float o2 = out_w[2 * 64 + lane];
        float* c = ws + 128;
        // c layout: [0..3]=G00,G01,G02,G11  [4..7]=G12,G22,M00,M01
        //           [8..11]=M02,M10,M11,M12 [12..15]=M20,M21,M22,bn
        //           [16..19]=v0,v1,v2,ngamma [20..23]=g0,g1,g2,alpha
        //           [24..27]=cc,W0,W1,W2     [28..31]=ob0,ob1,ob2,pad
        if (wave == 0) {
            float r0 = wred64(w0 * w0), r1 = wred64(w0 * w1), r2 = wred64(w0 * w2);
            float r3 = wred64(w1 * w1), r4 = wred64(w1 * w2), r5 = wred64(w2 * w2);
            if (lane == 0) { c[0]=r0; c[1]=r1; c[2]=r2; c[3]=r3; c[4]=r4; c[5]=r5; }
        } else if (wave == 1) {
            float r0 = wred64(o0 * w0), r1 = wred64(o0 * w1), r2 = wred64(o0 * w2);
            float r3 = wred64(o1 * w0), r4 = wred64(o1 * w1), r5 = wred64(o1 * w2);
            if (lane == 0) { c[6]=r0; c[7]=r1; c[8]=r2; c[9]=r3; c[10]=r4; c[11]=r5; }
        } else if (wave == 2) {
            float r0 = wred64(o2 * w0), r1 = wred64(o2 * w1), r2 = wred64(o2 * w2);
            float r3 = wred64(zb * zb), r4 = wred64(o0 * zb), r5 = wred64(o1 * zb);
            if (lane == 0) { c[12]=r0; c[13]=r1; c[14]=r2; c[15]=r3; c[16]=r4; c[17]=r5; }
        } else {
            float r0 = wred64(o2 * zb), r1 = wred64(w0 * zb);
            float r2 = wred64(w1 * zb), r3 = wred64(w2 * zb);
            if (lane == 0) {
                c[18] = r0;                  // v2
                c[20] = r1; c[21] = r2; c[22] = r3;   // g
                c[19] = -__expf(log_gamma[0]);        // ngamma
                c[23] = alpha_p[0];
                c[24] = c_p[0];
                float a = wv[0], bb = wv[1], d = wv[2];
                float inv = 1.f / (a + bb + d + 1e-8f);
                c[25] = a * inv; c[26] = bb * inv; c[27] = d * inv;  // W0,W1,W2
                c[28] = out_bias[0]; c[29] = out_bias[1]; c[30] = out_bias[2];
                c[31] = 0.f;
            }
        }
    }
}

__global__ __launch_bounds__(256) void fuse_kernel(
    const float* __restrict__ z,   // (16,3,256,256)
    const float* __restrict__ ws,
    float* __restrict__ out)       // (16,3,256,256)
{
    const int blk = blockIdx.x;
    const int b   = blk >> 5;                               // 32 blocks per batch
    const int p   = ((blk & 31) << 11) + (threadIdx.x << 3); // 8 px/thread

    // Issue the 6 z vector-loads FIRST so HBM/L3 latency overlaps the
    // (scalar) ws-constant prologue.
    const float* zb = z + (size_t)b * 3 * HW_PIX + p;
    f4 a0 = ld4(zb),            a1 = ld4(zb + 4);
    f4 b0 = ld4(zb + HW_PIX),   b1 = ld4(zb + HW_PIX + 4);
    f4 c0 = ld4(zb + 2*HW_PIX), c1 = ld4(zb + 2*HW_PIX + 4);

    const f4* C4 = (const f4*)(ws + 128);
    const f4 f0 = C4[0], f1 = C4[1], f2 = C4[2], f3 = C4[3];
    const f4 f4v = C4[4], f5 = C4[5], f6 = C4[6], f7 = C4[7];
    const float G00=f0[0], G01=f0[1], G02=f0[2], G11=f0[3];
    const float G12=f1[0], G22=f1[1], M00=f1[2], M01=f1[3];
    const float M02=f2[0], M10=f2[1], M11=f2[2], M12=f2[3];
    const float M20=f3[0], M21=f3[1], M22=f3[2], bn =f3[3];
    const float v0=f4v[0], v1=f4v[1], v2=f4v[2], ngamma=f4v[3];
    const float g0=f5[0], g1=f5[1], g2=f5[2], alpha=f5[3];
    const float cc=f6[0], W0=f6[1], W1=f6[2], W2=f6[3];
    const float ob0=f7[0], ob1=f7[1], ob2=f7[2];

    const f4* pb4 = (const f4*)(ws + b * 8);
    const f4 pbA = pb4[0], pbB = pb4[1];
    const float u0=pbA[0], u1=pbA[1], u2=pbA[2], s=pbA[3];
    const float d0 = bn + pbB[0];
    const float e0 = g0 - u0, e1 = g1 - u1, e2 = g2 - u2;

    float X[8], Y[8], Z[8], O0[8], O1[8], O2[8];
#pragma unroll
    for (int j = 0; j < 4; ++j) {
        X[j] = a0[j]; X[j+4] = a1[j];
        Y[j] = b0[j]; Y[j+4] = b1[j];
        Z[j] = c0[j]; Z[j+4] = c1[j];
    }

#pragma unroll
    for (int j = 0; j < 8; ++j) {
        const float x = X[j], y = Y[j], zc = Z[j];
        const float klin = fmaf(x, u0, fmaf(y, u1, fmaf(zc, u2, s)));
        const float quad = x * fmaf(2.f, fmaf(G01, y, G02 * zc), G00 * x)
                         + y * fmaf(2.f, G12 * zc, G11 * y)
                         + G22 * zc * zc;
        const float dist = quad + 2.f * fmaf(e0, x, fmaf(e1, y, e2 * zc)) + d0;
        const float krbf = __expf(ngamma * dist);
        float kp = fmaf(alpha, klin, cc);
        kp = kp * kp;
        const float k = fmaf(W0, krbf, fmaf(W1, klin, W2 * kp));
        const float sig = 1.f / (1.f + __expf(-k));
        const float scale = 1.f + sig;

        const float m0 = fmaf(M00, x, fmaf(M01, y, fmaf(M02, zc, v0)));
        const float m1 = fmaf(M10, x, fmaf(M11, y, fmaf(M12, zc, v1)));
        const float m2 = fmaf(M20, x, fmaf(M21, y, fmaf(M22, zc, v2)));
        O0[j] = fmaf(scale, m0, ob0);
        O1[j] = fmaf(scale, m1, ob1);
        O2[j] = fmaf(scale, m2, ob2);
    }

    // Plain (cached) stores: the 12.6 MB output fits in L2+L3, so the cache
    // absorbs the write burst instead of forcing HBM writes in-window.
    float* ob = out + (size_t)b * 3 * HW_PIX + p;
    f4 r;
    r[0]=O0[0]; r[1]=O0[1]; r[2]=O0[2]; r[3]=O0[3]; st4(ob, r);
    r[0]=O0[4]; r[1]=O0[5]; r[2]=O0[6]; r[3]=O0[7]; st4(ob + 4, r);
    r[0]=O1[0]; r[1]=O1[1]; r[2]=O1[2]; r[3]=O1[3]; st4(ob + HW_PIX, r);
    r[0]=O1[4]; r[1]=O1[5]; r[2]=O1[6]; r[3]=O1[7]; st4(ob + HW_PIX + 4, r);
    r[0]=O2[0]; r[1]=O2[1]; r[2]=O2[2]; r[3]=O2[3]; st4(ob + 2*HW_PIX, r);
    r[0]=O2[4]; r[1]=O2[5]; r[2]=O2[6]; r[3]=O2[7]; st4(ob + 2*HW_PIX + 4, r);
}

extern "C" void kernel_launch(void* const* d_in, const int* in_sizes, int n_in,
                              void* d_out, int out_size, void* d_ws, size_t ws_size,
                              hipStream_t stream) {
    const float* z           = (const float*)d_in[0];
    const float* text_vec    = (const float*)d_in[1];
    const float* z_proj_w    = (const float*)d_in[2];
    const float* z_proj_b    = (const float*)d_in[3];
    const float* text_proj_w = (const float*)d_in[4];
    const float* text_proj_b = (const float*)d_in[5];
    const float* out_w       = (const float*)d_in[6];
    const float* out_b       = (const float*)d_in[7];
    const float* log_gamma   = (const float*)d_in[8];
    const float* alpha       = (const float*)d_in[9];
    const float* c           = (const float*)d_in[10];
    const float* w           = (const float*)d_in[11];
    float* out = (float*)d_out;
    float* ws  = (float*)d_ws;
    (void)in_sizes; (void)n_in; (void)out_size; (void)ws_size;

    prep_kernel<<<17, 256, 0, stream>>>(text_vec, text_proj_w, text_proj_b,
                                        z_proj_w, z_proj_b, out_w, out_b,
                                        log_gamma, alpha, c, w, ws);
    fuse_kernel<<<512, 256, 0, stream>>>(z, ws, out);
}